// Round 9
// baseline (86.966 us; speedup 1.0000x reference)
//
#include <hip/hip_runtime.h>

#define N_ 256
#define C_ 2048
#define HW_ 49
#define CPB 64
#define NCC 32          // 64-ch chunks in k_mul / k_main fallback
#define NCHUNK 8        // 256-ch chunks in k_pool_gate / k_poolc

// ============================================================================
// MAIN PATH
// ============================================================================

// ---- kernel 1: fused channel-pool partials + W/H pools + conv -> gates ----
// grid (8, N). Each block owns 256 channels (+3 halo each side).
// LDS: sx[3584] + pool_lo[4224] + pool_hi[4224] + part[490] + s_w[112]
//    = 12634 floats = 50.5 KB -> 3 blocks/CU.
// Pool rows are 16 B (4 floats) split lo/hi: b128 reads get 8 balanced
// bank-starts (the r7 layout that measured conflict-light).
__global__ __launch_bounds__(256) void k_pool_gate(const float* __restrict__ x,
    const float* __restrict__ cw, const float* __restrict__ cb,
    const float* __restrict__ bnw, const float* __restrict__ bnb,
    const float* __restrict__ bnrm, const float* __restrict__ bnrv,
    float* __restrict__ psum, float* __restrict__ pmax,
    float* __restrict__ gch_g, float* __restrict__ gcw_g) {
  const int bc = blockIdx.x, n = blockIdx.y;
  const int t = threadIdx.x;

  __shared__ __align__(16) float sx[3584];          // staging; later gate transpose
  __shared__ __align__(16) float pool_lo[4 * 264 * 4];  // [f][pc][k=0..3]
  __shared__ __align__(16) float pool_hi[4 * 264 * 4];  // [f][pc][k=4..6,+pad]
  __shared__ float part_s[HW_][5];
  __shared__ float part_m[HW_][5];
  __shared__ __align__(16) float s_w[112];          // [2][7][8] weights, q-padded

  if (t < 112) {
    int i2w = t / 56, rem = t % 56, p = rem / 8, q = rem % 8;
    s_w[t] = (q < 7) ? cw[i2w * 49 + p * 7 + q] : 0.f;
  }

  float sm = 0.f, mx = -3.4e38f;        // channel-pool partial regs
  const int hwp = t / 5, sp = t % 5;

  const float4* xv = (const float4*)(x + ((size_t)n * C_ + (size_t)bc * 256) * HW_);
  float4* sv = (float4*)sx;
  #pragma unroll
  for (int pass = 0; pass < 4; ++pass) {
    for (int v = t; v < 784; v += 256) sv[v] = xv[pass * 784 + v];
    __syncthreads();
    // channel-pool partials (mean/max over C) for g_hw
    if (t < 245) {
      #pragma unroll
      for (int j = 0; j < 13; ++j) {
        int c = sp * 13 + j;
        if (c < CPB) { float a = sx[c * HW_ + hwp]; sm += a; mx = fmaxf(mx, a); }
      }
    }
    // W-pools / H-pools for these 64 channels
    for (int i = t; i < 448; i += 256) {
      int lc = i / 7, k = i % 7;
      int base = lc * HW_;
      float s1 = 0.f, m1 = -3.4e38f, s2 = 0.f, m2 = -3.4e38f;
      #pragma unroll
      for (int j = 0; j < 7; ++j) {
        float a = sx[base + k * 7 + j]; s1 += a; m1 = fmaxf(m1, a);  // h=k, vary w
        float b = sx[base + j * 7 + k]; s2 += b; m2 = fmaxf(m2, b);  // w=k, vary h
      }
      int pc = pass * 64 + 3 + lc;
      int kk = k & 3;
      float* pb = (k < 4) ? pool_lo : pool_hi;
      pb[(0 * 264 + pc) * 4 + kk] = s1 * (1.f / 7.f);  // f0: g_ch mean
      pb[(1 * 264 + pc) * 4 + kk] = m1;                // f1: g_ch max
      pb[(2 * 264 + pc) * 4 + kk] = s2 * (1.f / 7.f);  // f2: g_cw mean
      pb[(3 * 264 + pc) * 4 + kk] = m2;                // f3: g_cw max
    }
    __syncthreads();
  }

  // halo channel pools (3 low + 3 high): direct global reads, zero outside [0,C)
  if (t < 42) {
    int hc = t / 7, k = t % 7;
    int pc = (hc < 3) ? hc : 259 + (hc - 3);
    int c = bc * 256 - 3 + pc;
    float s1 = 0.f, m1 = 0.f, s2 = 0.f, m2 = 0.f;   // zero-pad = 0 for both planes
    if (c >= 0 && c < C_) {
      m1 = -3.4e38f; m2 = -3.4e38f;
      const float* xp = x + ((size_t)n * C_ + c) * HW_;
      #pragma unroll
      for (int j = 0; j < 7; ++j) {
        float a = xp[k * 7 + j]; s1 += a; m1 = fmaxf(m1, a);
        float b = xp[j * 7 + k]; s2 += b; m2 = fmaxf(m2, b);
      }
      s1 *= (1.f / 7.f); s2 *= (1.f / 7.f);
    }
    int kk = k & 3;
    float* pb = (k < 4) ? pool_lo : pool_hi;
    pb[(0 * 264 + pc) * 4 + kk] = s1;
    pb[(1 * 264 + pc) * 4 + kk] = m1;
    pb[(2 * 264 + pc) * 4 + kk] = s2;
    pb[(3 * 264 + pc) * 4 + kk] = m2;
  }
  if (t < 245) { part_s[hwp][sp] = sm; part_m[hwp][sp] = mx; }
  __syncthreads();

  // finalize channel-pool partials
  if (t < HW_) {
    float s2 = 0.f, m2 = -3.4e38f;
    #pragma unroll
    for (int k = 0; k < 5; ++k) { s2 += part_s[t][k]; m2 = fmaxf(m2, part_m[t][k]); }
    size_t o = ((size_t)n * NCHUNK + bc) * HW_ + t;
    psum[o] = s2; pmax[o] = m2;
  }

  // conv: one output channel per thread (global channel bc*256 + t)
  const float cb0 = cb[0];
  const float sc1 = bnw[1] * rsqrtf(bnrv[1] + 1e-5f), rm1 = bnrm[1], sh1 = bnb[1];
  const float sc2 = bnw[2] * rsqrtf(bnrv[2] + 1e-5f), rm2 = bnrm[2], sh2 = bnb[2];
  float g0[7] = {0, 0, 0, 0, 0, 0, 0};
  float g1[7] = {0, 0, 0, 0, 0, 0, 0};
  #pragma unroll
  for (int f = 0; f < 4; ++f) {
    const float* Wb = s_w + (f & 1) * 56;
    #pragma unroll
    for (int p = 0; p < 7; ++p) {
      int ri = (f * 264 + t + p) * 4;          // rows t..t+6 = channels (c-3..c+3)
      float4 lo4 = *(const float4*)(pool_lo + ri);
      float4 hi4 = *(const float4*)(pool_hi + ri);
      float row[7] = {lo4.x, lo4.y, lo4.z, lo4.w, hi4.x, hi4.y, hi4.z};
      float4 w0 = *(const float4*)(Wb + p * 8);
      float4 w1 = *(const float4*)(Wb + p * 8 + 4);
      float wr[7] = {w0.x, w0.y, w0.z, w0.w, w1.x, w1.y, w1.z};
      #pragma unroll
      for (int q = 0; q < 7; ++q)
        #pragma unroll
        for (int k = 0; k < 7; ++k) {
          int c = k + q - 3;                   // compile-time after unroll
          if (c >= 0 && c < 7) {
            if (f < 2) g0[k] += row[c] * wr[q];
            else       g1[k] += row[c] * wr[q];
          }
        }
    }
  }
  // BN + relu + sigmoid; stash in sx (free now) for coalesced global write
  #pragma unroll
  for (int k = 0; k < 7; ++k) {
    float y0 = (g0[k] + cb0 - rm1) * sc1 + sh1;
    y0 = fmaxf(y0, 0.f);
    sx[t * 7 + k] = 1.f / (1.f + __expf(-y0));
    float y1 = (g1[k] + cb0 - rm2) * sc2 + sh2;
    y1 = fmaxf(y1, 0.f);
    sx[1792 + t * 7 + k] = 1.f / (1.f + __expf(-y1));
  }
  __syncthreads();
  {
    size_t goff = ((size_t)n * C_ + (size_t)bc * 256) * 7;   // float4-aligned
    const float4* gs = (const float4*)sx;
    float4* d1 = (float4*)(gch_g + goff);
    float4* d2 = (float4*)(gcw_g + goff);
    for (int v = t; v < 896; v += 256) {
      if (v < 448) d1[v] = gs[v];
      else         d2[v - 448] = gs[v];
    }
  }
}

// ---- kernel 2: reduce chunk partials, compute g_hw gate per n ----
__global__ __launch_bounds__(64) void k_ghw(const float* __restrict__ psum,
                                            const float* __restrict__ pmax,
                                            const float* __restrict__ cw,
                                            const float* __restrict__ cb,
                                            const float* __restrict__ bnw,
                                            const float* __restrict__ bnb,
                                            const float* __restrict__ bnrm,
                                            const float* __restrict__ bnrv,
                                            float* __restrict__ ghw) {
  const int n = blockIdx.x;
  const int t = threadIdx.x;
  __shared__ float p2c[2][13][13];
  __shared__ float s_cw[98];

  for (int i = t; i < 2 * 13 * 13; i += 64) ((float*)p2c)[i] = 0.f;
  for (int i = t; i < 98; i += 64) s_cw[i] = cw[i];
  __syncthreads();

  if (t < HW_) {
    float sm = 0.f, mx = -3.4e38f;
    const float* ps = psum + (size_t)n * NCHUNK * HW_ + t;
    const float* pm = pmax + (size_t)n * NCHUNK * HW_ + t;
    #pragma unroll
    for (int cc = 0; cc < NCHUNK; ++cc) {
      sm += ps[cc * HW_];
      mx = fmaxf(mx, pm[cc * HW_]);
    }
    p2c[0][t / 7 + 3][t % 7 + 3] = sm * (1.f / C_);
    p2c[1][t / 7 + 3][t % 7 + 3] = mx;
  }
  __syncthreads();

  if (t < HW_) {
    int a = t / 7, b = t % 7;
    float y = cb[0];
    #pragma unroll
    for (int i2 = 0; i2 < 2; ++i2)
      #pragma unroll
      for (int p = 0; p < 7; ++p)
        #pragma unroll
        for (int q = 0; q < 7; ++q)
          y += p2c[i2][a + p][b + q] * s_cw[i2 * 49 + p * 7 + q];
    float sc = bnw[0] * rsqrtf(bnrv[0] + 1e-5f);
    y = (y - bnrm[0]) * sc + bnb[0];
    y = fmaxf(y, 0.f);
    ghw[n * HW_ + t] = 1.f / (1.f + __expf(-y));
  }
}

// ---- kernel 3: pure streaming fused multiply ----
// LDS 3.8 KB, 1 barrier -> occupancy-unconstrained, memory-bound.
__global__ __launch_bounds__(256) void k_mul(const float* __restrict__ x,
    const float* __restrict__ ghw, const float* __restrict__ gch_g,
    const float* __restrict__ gcw_g, float* __restrict__ out) {
  const int cc = blockIdx.x;
  const int n  = (N_ - 1) - blockIdx.y;   // reverse n: read freshest L3 lines first
  const int c0 = cc * CPB;
  const int t  = threadIdx.x;

  __shared__ float sg[960];  // [0,448) gch rows, [448,896) gcw rows, [896,945) ghw

  {
    const float* g1 = gch_g + ((size_t)n * C_ + c0) * 7;
    const float* g2 = gcw_g + ((size_t)n * C_ + c0) * 7;
    for (int i = t; i < 945; i += 256) {
      float v;
      if (i < 448)      v = g1[i];
      else if (i < 896) v = g2[i - 448];
      else              v = ghw[n * HW_ + (i - 896)];
      sg[i] = v;
    }
  }
  __syncthreads();
  const float* gch = sg;
  const float* gcw = sg + 448;
  const float* s_ghw = sg + 896;

  const float4* xv = (const float4*)(x + ((size_t)n * C_ + c0) * HW_);
  float4* outv = (float4*)(out + ((size_t)n * C_ + c0) * HW_);
  for (int v = t; v < 784; v += 256) {
    float4 q = xv[v];
    int e0 = v * 4;
    int cj = e0 / 49;
    int hw0 = e0 - cj * 49;
    float r0 = q.x, r1 = q.y, r2 = q.z, r3 = q.w;
    {
      int hw = hw0;
      int cjj = cj + (hw >= 49); hw -= (hw >= 49) ? 49 : 0;
      int h = (hw * 37) >> 8, w2 = hw - h * 7;
      r0 *= (s_ghw[hw] + gch[cjj * 7 + h] + gcw[cjj * 7 + w2]) * (1.f / 3.f);
    }
    {
      int hw = hw0 + 1;
      int cjj = cj + (hw >= 49); hw -= (hw >= 49) ? 49 : 0;
      int h = (hw * 37) >> 8, w2 = hw - h * 7;
      r1 *= (s_ghw[hw] + gch[cjj * 7 + h] + gcw[cjj * 7 + w2]) * (1.f / 3.f);
    }
    {
      int hw = hw0 + 2;
      int cjj = cj + (hw >= 49); hw -= (hw >= 49) ? 49 : 0;
      int h = (hw * 37) >> 8, w2 = hw - h * 7;
      r2 *= (s_ghw[hw] + gch[cjj * 7 + h] + gcw[cjj * 7 + w2]) * (1.f / 3.f);
    }
    {
      int hw = hw0 + 3;
      int cjj = cj + (hw >= 49); hw -= (hw >= 49) ? 49 : 0;
      int h = (hw * 37) >> 8, w2 = hw - h * 7;
      r3 *= (s_ghw[hw] + gch[cjj * 7 + h] + gcw[cjj * 7 + w2]) * (1.f / 3.f);
    }
    outv[v] = make_float4(r0, r1, r2, r3);
  }
}

// ============================================================================
// FALLBACK PATH (round-8 kernels) — used only if ws is too small for gates
// ============================================================================

__global__ __launch_bounds__(256) void k_poolc_fb(const float* __restrict__ x,
                                                  float* __restrict__ psum,
                                                  float* __restrict__ pmax) {
  const int bc = blockIdx.x, n = blockIdx.y;
  const int t = threadIdx.x;
  __shared__ __align__(16) float sx[CPB * HW_];
  __shared__ float part_s[HW_][5];
  __shared__ float part_m[HW_][5];

  float sm = 0.f, mx = -3.4e38f;
  const int hw = t / 5, s = t % 5;

  const float4* xv = (const float4*)(x + ((size_t)n * C_ + (size_t)bc * 256) * HW_);
  #pragma unroll
  for (int pass = 0; pass < 4; ++pass) {
    float4* sv = (float4*)sx;
    for (int v = t; v < 784; v += 256) sv[v] = xv[pass * 784 + v];
    __syncthreads();
    if (t < 245) {
      #pragma unroll
      for (int j = 0; j < 13; ++j) {
        int c = s * 13 + j;
        if (c < CPB) { float a = sx[c * HW_ + hw]; sm += a; mx = fmaxf(mx, a); }
      }
    }
    __syncthreads();
  }
  if (t < 245) { part_s[hw][s] = sm; part_m[hw][s] = mx; }
  __syncthreads();
  if (t < HW_) {
    float s2 = 0.f, m2 = -3.4e38f;
    #pragma unroll
    for (int k = 0; k < 5; ++k) { s2 += part_s[t][k]; m2 = fmaxf(m2, part_m[t][k]); }
    size_t o = ((size_t)n * NCHUNK + bc) * HW_ + t;
    psum[o] = s2; pmax[o] = m2;
  }
}

#define CHB(lc) ((lc) * HW_ + ((lc) >= 3 ? 1 : 0))

__global__ __launch_bounds__(256, 6) void k_main_fb(const float* __restrict__ x,
    const float* __restrict__ ghw,
    const float* __restrict__ cw, const float* __restrict__ cb,
    const float* __restrict__ bnw, const float* __restrict__ bnb,
    const float* __restrict__ bnrm, const float* __restrict__ bnrv,
    float* __restrict__ out) {
  const int cc = blockIdx.x;
  const int n  = (N_ - 1) - blockIdx.y;
  const int c0 = cc * CPB;
  const int t  = threadIdx.x;

  __shared__ __align__(16) float sx[3432];
  __shared__ __align__(16) float pool_lo[1120];
  __shared__ __align__(16) float pool_hi[1120];
  __shared__ float gch[448];
  __shared__ float gcw[448];
  __shared__ __align__(16) float s_w[112];
  __shared__ float s_ghw[49];

  const int conv = t & 1, i2 = (t >> 1) & 1, cl = t >> 2;
  const int bi = 1 + conv;
  const float cb0 = cb[0];
  const float sc_bn = bnw[bi] * rsqrtf(bnrv[bi] + 1e-5f);
  const float rm_bn = bnrm[bi];
  const float sh_bn = bnb[bi];

  if (t < 112) {
    int i2w = t / 56, rem = t % 56, p = rem / 8, q = rem % 8;
    s_w[t] = (q < 7) ? cw[i2w * 49 + p * 7 + q] : 0.f;
  }
  if (t < HW_) s_ghw[t] = ghw[n * HW_ + t];
  for (int i = t; i < 2 * 3 * HW_; i += 256) {
    int side = i / 147, off = i % 147;
    int lc = side ? (67 + off / HW_) : (off / HW_);
    int c = c0 - 3 + lc;
    float vv = 0.f;
    if (c >= 0 && c < C_) vv = x[((size_t)n * C_ + c) * HW_ + off % HW_];
    sx[CHB(lc) + off % HW_] = vv;
  }
  const float4* xv = (const float4*)(x + ((size_t)n * C_ + c0) * HW_);
  float4* sxv = (float4*)(sx + 148);
  for (int v = t; v < 784; v += 256) sxv[v] = xv[v];
  __syncthreads();

  for (int i = t; i < 70 * 7; i += 256) {
    int lc = i / 7, k = i % 7;
    int base = CHB(lc);
    float s1 = 0.f, m1 = -3.4e38f, s2 = 0.f, m2 = -3.4e38f;
    #pragma unroll
    for (int j = 0; j < 7; ++j) {
      float a = sx[base + k * 7 + j]; s1 += a; m1 = fmaxf(m1, a);
      float b = sx[base + j * 7 + k]; s2 += b; m2 = fmaxf(m2, b);
    }
    float* pb = (k < 4) ? pool_lo : pool_hi;
    int kk = k & 3;
    pb[((conv * 0 + 0) * 70 + lc) * 4 + kk + 0 * 280] = 0.f; // (placeholder avoided below)
    pb[(0 * 70 + lc) * 4 + kk] = s1 * (1.f / 7.f);
    pb[(1 * 70 + lc) * 4 + kk] = m1;
    pb[(2 * 70 + lc) * 4 + kk] = s2 * (1.f / 7.f);
    pb[(3 * 70 + lc) * 4 + kk] = m2;
  }
  __syncthreads();

  {
    const int f = conv * 2 + i2;
    const float* Wb = s_w + i2 * 56;
    float acc[7] = {0.f, 0.f, 0.f, 0.f, 0.f, 0.f, 0.f};
    #pragma unroll
    for (int p = 0; p < 7; ++p) {
      int ri = (f * 70 + cl + p) * 4;
      float4 r0 = *(const float4*)(pool_lo + ri);
      float4 r1 = *(const float4*)(pool_hi + ri);
      float row[7] = {r0.x, r0.y, r0.z, r0.w, r1.x, r1.y, r1.z};
      float4 w0 = *(const float4*)(Wb + p * 8);
      float4 w1 = *(const float4*)(Wb + p * 8 + 4);
      float wr[7] = {w0.x, w0.y, w0.z, w0.w, w1.x, w1.y, w1.z};
      #pragma unroll
      for (int q = 0; q < 7; ++q)
        #pragma unroll
        for (int k = 0; k < 7; ++k) {
          int c = k + q - 3;
          if (c >= 0 && c < 7) acc[k] += row[c] * wr[q];
        }
    }
    float fsum[7];
    #pragma unroll
    for (int k = 0; k < 7; ++k) fsum[k] = acc[k] + __shfl_xor(acc[k], 2, 64);
    if (i2 == 0) {
      float* gp = (conv ? gcw : gch) + cl * 7;
      #pragma unroll
      for (int k = 0; k < 7; ++k) {
        float y = (fsum[k] + cb0 - rm_bn) * sc_bn + sh_bn;
        y = fmaxf(y, 0.f);
        gp[k] = 1.f / (1.f + __expf(-y));
      }
    }
  }
  __syncthreads();

  float4* outv = (float4*)(out + ((size_t)n * C_ + c0) * HW_);
  for (int v = t; v < 784; v += 256) {
    float4 q = sxv[v];
    int e0 = v * 4;
    int cj = e0 / 49;
    int hw0 = e0 - cj * 49;
    float r[4] = {q.x, q.y, q.z, q.w};
    #pragma unroll
    for (int j = 0; j < 4; ++j) {
      int hw = hw0 + j;
      int cjj = cj + (hw >= 49);
      hw -= (hw >= 49) ? 49 : 0;
      int h = (hw * 37) >> 8, w2 = hw - h * 7;
      r[j] *= (s_ghw[hw] + gch[cjj * 7 + h] + gcw[cjj * 7 + w2]) * (1.f / 3.f);
    }
    outv[v] = make_float4(r[0], r[1], r[2], r[3]);
  }
}

// (fallback uses 70-row pools of 16B; sizes: 4*70*4=1120 each — matches decls)

extern "C" void kernel_launch(void* const* d_in, const int* in_sizes, int n_in,
                              void* d_out, int out_size, void* d_ws, size_t ws_size,
                              hipStream_t stream) {
  const float* x    = (const float*)d_in[0];
  const float* cw   = (const float*)d_in[1];
  const float* cb   = (const float*)d_in[2];
  const float* bnw  = (const float*)d_in[3];
  const float* bnb  = (const float*)d_in[4];
  const float* bnrm = (const float*)d_in[5];
  const float* bnrv = (const float*)d_in[6];
  float* out = (float*)d_out;

  float* psum  = (float*)d_ws;                          // N*8*49
  float* pmax  = psum + (size_t)N_ * NCHUNK * HW_;      // N*8*49
  float* ghw   = pmax + (size_t)N_ * NCHUNK * HW_;      // N*49
  float* gch_g = ghw + (size_t)N_ * HW_;                // N*C*7
  float* gcw_g = gch_g + (size_t)N_ * C_ * 7;           // N*C*7
  size_t need_floats = (size_t)N_ * NCHUNK * HW_ * 2 + (size_t)N_ * HW_
                     + (size_t)N_ * C_ * 7 * 2;

  if (ws_size >= need_floats * sizeof(float)) {
    k_pool_gate<<<dim3(NCHUNK, N_), 256, 0, stream>>>(
        x, cw, cb, bnw, bnb, bnrm, bnrv, psum, pmax, gch_g, gcw_g);
    k_ghw<<<dim3(N_), 64, 0, stream>>>(psum, pmax, cw, cb, bnw, bnb, bnrm, bnrv, ghw);
    k_mul<<<dim3(NCC, N_), 256, 0, stream>>>(x, ghw, gch_g, gcw_g, out);
  } else {
    k_poolc_fb<<<dim3(NCHUNK, N_), 256, 0, stream>>>(x, psum, pmax);
    k_ghw<<<dim3(N_), 64, 0, stream>>>(psum, pmax, cw, cb, bnw, bnb, bnrm, bnrv, ghw);
    k_main_fb<<<dim3(NCC, N_), 256, 0, stream>>>(x, ghw, cw, cb, bnw, bnb, bnrm, bnrv, out);
  }
}